// Round 8
// baseline (107.748 us; speedup 1.0000x reference)
//
#include <hip/hip_runtime.h>

#define K_DIM   4096
#define N_DIM   4096
#define M_ROWS  8192
#define KF      (K_DIM / 4)      // 1024 float4 per x/A row
#define NF      (N_DIM / 4)      // 1024 float4 per out row
#define KSPLIT  2
#define KHALF   (KF / KSPLIT)    // 512 float4 per K-half
#define KCH     128              // float4 per chunk
#define NCH     (KHALF / KCH)    // 4 chunks per block
#define NTILES  (M_ROWS / 16)    // 512 row tiles
#define TP_F4_STRIDE (M_ROWS * 16 / 4)   // 32768 float4 per k-partial slab

// ---------------------------------------------------------------------------
// Kernel 1: t partials. Grid = NTILES*KSPLIT blocks, 256 thr (4 waves x 4 rows).
// K-half processed in 4 chunks of 128 f4. Next chunk's A (regs->LDS) and x
// (reg double-buffer) are prefetched before current chunk's compute, hiding
// HBM latency under the ~2000cy FMA stream. Butterfly once per block.
__global__ __launch_bounds__(256, 2) void lora_xat(const float* __restrict__ x,
                                                   const float* __restrict__ A,
                                                   float* __restrict__ tpart) {
    __shared__ float4 Alds[16 * KCH];     // 32 KB

    const int tid  = threadIdx.x;
    const int wv   = tid >> 6;            // wave -> 4-row group
    const int lane = tid & 63;
    const int rb   = blockIdx.x >> 1;     // 16-row tile
    const int h    = blockIdx.x & 1;      // K half
    const int row0 = rb * 16 + wv * 4;
    const int kbase = h * KHALF;          // float4 units

    const float4* x4 = (const float4*)x;
    const float4* A4 = (const float4*)A;

    // staging map for A: idx = i*256 + tid -> (r, c)
    const int st_r[8] = {0,0,0,0,0,0,0,0}; (void)st_r;

    float4 areg[8];
    float4 xreg[2][8];                    // [buf][it*4 + j]

    // prime chunk 0
    #pragma unroll
    for (int i = 0; i < 8; ++i) {
        const int idx = i * 256 + tid;
        const int r = idx >> 7;
        const int c = idx & (KCH - 1);
        areg[i] = A4[r * KF + kbase + c];
    }
    #pragma unroll
    for (int it = 0; it < 2; ++it)
        #pragma unroll
        for (int j = 0; j < 4; ++j)
            xreg[0][it * 4 + j] =
                x4[(size_t)(row0 + j) * KF + kbase + it * 64 + lane];

    float red[64];
    #pragma unroll
    for (int v = 0; v < 64; ++v) red[v] = 0.f;

    #pragma unroll
    for (int ch = 0; ch < NCH; ++ch) {
        const int cur = ch & 1;           // static under full unroll
        const int nxt = cur ^ 1;

        __syncthreads();                  // previous compute done, LDS free
        #pragma unroll
        for (int i = 0; i < 8; ++i) {
            const int idx = i * 256 + tid;
            Alds[idx] = areg[i];
        }
        // issue next chunk's global loads (in flight during compute)
        if (ch + 1 < NCH) {
            const int kc = kbase + (ch + 1) * KCH;
            #pragma unroll
            for (int i = 0; i < 8; ++i) {
                const int idx = i * 256 + tid;
                const int r = idx >> 7;
                const int c = idx & (KCH - 1);
                areg[i] = A4[r * KF + kc + c];
            }
            #pragma unroll
            for (int it = 0; it < 2; ++it)
                #pragma unroll
                for (int j = 0; j < 4; ++j)
                    xreg[nxt][it * 4 + j] =
                        x4[(size_t)(row0 + j) * KF + kc + it * 64 + lane];
        }
        __syncthreads();                  // Alds ready

        #pragma unroll
        for (int it = 0; it < 2; ++it) {
            const int kl = it * 64 + lane;
            #pragma unroll
            for (int r = 0; r < 16; ++r) {
                const float4 av = Alds[r * KCH + kl];
                #pragma unroll
                for (int j = 0; j < 4; ++j) {
                    float a = red[j * 16 + r];
                    const float4 xv = xreg[cur][it * 4 + j];
                    a = fmaf(xv.x, av.x, a);
                    a = fmaf(xv.y, av.y, a);
                    a = fmaf(xv.z, av.z, a);
                    a = fmaf(xv.w, av.w, a);
                    red[j * 16 + r] = a;
                }
            }
        }
    }

    // in-wave butterfly (once per block): lane l ends with sum of red[l]
    #pragma unroll
    for (int s = 0; s < 6; ++s) {
        const int m = 1 << s;
        const int b = (lane >> s) & 1;
        #pragma unroll
        for (int u = 0; u < (64 >> (s + 1)); ++u) {
            const float lo = red[2 * u];
            const float hi = red[2 * u + 1];
            const float send = b ? lo : hi;
            const float recv = __shfl_xor(send, m, 64);
            const float kept = b ? hi : lo;
            red[u] = kept + recv;
        }
    }

    // contiguous 256B store per wave: tpart[h][row0 + (lane>>4)][lane&15]
    tpart[((size_t)h * M_ROWS + row0) * 16 + lane] = red[0];
}

// ---------------------------------------------------------------------------
// Kernel 2: out = t @ B^T. Block = 16 rows x 1024 cols, 256 threads.
// Thread owns 4 consecutive output cols; B values for those cols live in
// registers (contiguous 256B per thread, L1/L2-hot). tpart (2 slabs) summed
// into 1 KB LDS, broadcast. Stores: 1KB coalesced bursts.
__global__ __launch_bounds__(256, 4) void lora_tb(const float* __restrict__ tpart,
                                                  const float* __restrict__ B,
                                                  float* __restrict__ out) {
    __shared__ float4 t_s4[64];           // 16 rows x 16 r

    const int tid = threadIdx.x;
    const int rb  = blockIdx.x >> 2;      // 16-row tile
    const int cb  = blockIdx.x & 3;       // 1024-col chunk

    // B into registers: 4 cols x 16 r = 256B contiguous per thread
    const int o0 = cb * 1024 + tid * 4;   // first of 4 output cols
    float4 breg[4][4];
    const float4* B4 = (const float4*)B;
    #pragma unroll
    for (int j = 0; j < 4; ++j)
        #pragma unroll
        for (int q = 0; q < 4; ++q)
            breg[j][q] = B4[(size_t)(o0 + j) * 4 + q];

    if (tid < 64) {
        const float4* p4 = (const float4*)tpart;
        float4 a = p4[(size_t)rb * 64 + tid];
        const float4 b = p4[(size_t)TP_F4_STRIDE + rb * 64 + tid];
        a.x += b.x; a.y += b.y; a.z += b.z; a.w += b.w;
        t_s4[tid] = a;                    // t[rb*16 + ...] row*4+q layout
    }
    __syncthreads();

    float4* out4 = (float4*)out;
    const int c4 = cb * 256 + tid;        // float4 column index

    #pragma unroll
    for (int row = 0; row < 16; ++row) {
        float4 tq[4];
        #pragma unroll
        for (int q = 0; q < 4; ++q)
            tq[q] = t_s4[row * 4 + q];    // LDS broadcast (same addr all lanes)
        float o0v = 0.f, o1v = 0.f, o2v = 0.f, o3v = 0.f;
        #pragma unroll
        for (int r = 0; r < 16; ++r) {
            const float4 tv4 = tq[r >> 2];
            const float tv = ((r & 3) == 0) ? tv4.x :
                             ((r & 3) == 1) ? tv4.y :
                             ((r & 3) == 2) ? tv4.z : tv4.w;
            o0v = fmaf(tv, ((const float*)&breg[0][0])[r], o0v);
            o1v = fmaf(tv, ((const float*)&breg[1][0])[r], o1v);
            o2v = fmaf(tv, ((const float*)&breg[2][0])[r], o2v);
            o3v = fmaf(tv, ((const float*)&breg[3][0])[r], o3v);
        }
        const float4 o = {o0v, o1v, o2v, o3v};
        out4[(size_t)(rb * 16 + row) * NF + c4] = o;
    }
}

extern "C" void kernel_launch(void* const* d_in, const int* in_sizes, int n_in,
                              void* d_out, int out_size, void* d_ws, size_t ws_size,
                              hipStream_t stream) {
    const float* x = (const float*)d_in[0];            // [4,2048,4096]
    const float* B = (const float*)d_in[1];            // [4096,16]
    const float* A = (const float*)d_in[2];            // [16,4096]
    float* out = (float*)d_out;                        // [4,2048,4096]

    float* tpart = (float*)d_ws;                       // [2][8192][16], 1 MB

    lora_xat<<<NTILES * KSPLIT, 256, 0, stream>>>(x, A, tpart);
    lora_tb<<<NTILES * (N_DIM / 1024), 256, 0, stream>>>(tpart, B, out);
}

// Round 10
// 83.229 us; speedup vs baseline: 1.2946x; 1.2946x over previous
//
#include <hip/hip_runtime.h>

#define K_DIM   4096
#define N_DIM   4096
#define M_ROWS  8192
#define KF      (K_DIM / 4)      // 1024 float4 per x/A row
#define NF      (N_DIM / 4)      // 1024 float4 per out row
#define KSPLIT  2
#define KHALF   (KF / KSPLIT)    // 512 float4 per K-half
#define KCH     128              // float4 per chunk
#define NCH     (KHALF / KCH)    // 4 chunks per K-half
#define NTILES  (M_ROWS / 16)    // 512 row tiles
#define TP_F4_STRIDE (M_ROWS * 16 / 4)   // 32768 float4 per k-partial slab

// ---------------------------------------------------------------------------
// Kernel 1: t partials. Grid = NTILES*KSPLIT = 1024 blocks, 256 thr
// (4 waves x 4 rows = 16 rows). K-half processed as 4 chunks of 128 f4:
// per chunk stage A (32 KB) into LDS via regs (areg dies before xv8 lives,
// keeping peak regs ~= red[64] + 8 float4), then 2 FMA iterations.
// Butterfly reduction ONCE per block (8x amortized vs KSPLIT=8).
// NO register double-buffering (round-8 spill lesson, rule #20).
__global__ __launch_bounds__(256) void lora_xat(const float* __restrict__ x,
                                                const float* __restrict__ A,
                                                float* __restrict__ tpart) {
    __shared__ float4 Alds[16 * KCH];     // 32 KB

    const int tid  = threadIdx.x;
    const int wv   = tid >> 6;            // wave -> 4-row group
    const int lane = tid & 63;
    const int rb   = blockIdx.x >> 1;     // 16-row tile
    const int h    = blockIdx.x & 1;      // K half
    const int row0 = rb * 16 + wv * 4;
    const int kbase = h * KHALF;          // float4 units

    const float4* x4 = (const float4*)x;
    const float4* A4 = (const float4*)A;

    float red[64];
    #pragma unroll
    for (int v = 0; v < 64; ++v) red[v] = 0.f;

    for (int ch = 0; ch < NCH; ++ch) {    // runtime loop, no unroll needed
        const int kc = kbase + ch * KCH;

        __syncthreads();                  // prev chunk's LDS reads done
        {
            float4 areg[8];
            #pragma unroll
            for (int i = 0; i < 8; ++i) {
                const int idx = i * 256 + tid;
                areg[i] = A4[(idx >> 7) * KF + kc + (idx & (KCH - 1))];
            }
            #pragma unroll
            for (int i = 0; i < 8; ++i)
                Alds[i * 256 + tid] = areg[i];
        }                                 // areg dead here
        __syncthreads();                  // Alds ready

        float4 xv8[8];                    // this chunk's x: 2 its x 4 rows
        #pragma unroll
        for (int it = 0; it < 2; ++it)
            #pragma unroll
            for (int j = 0; j < 4; ++j)
                xv8[it * 4 + j] =
                    x4[(size_t)(row0 + j) * KF + kc + it * 64 + lane];

        #pragma unroll
        for (int it = 0; it < 2; ++it) {
            const int kl = it * 64 + lane;
            #pragma unroll
            for (int r = 0; r < 16; ++r) {
                const float4 av = Alds[r * KCH + kl];   // conflict-free b128
                #pragma unroll
                for (int j = 0; j < 4; ++j) {
                    float a = red[j * 16 + r];
                    const float4 xv = xv8[it * 4 + j];
                    a = fmaf(xv.x, av.x, a);
                    a = fmaf(xv.y, av.y, a);
                    a = fmaf(xv.z, av.z, a);
                    a = fmaf(xv.w, av.w, a);
                    red[j * 16 + r] = a;
                }
            }
        }
    }

    // in-wave butterfly (once per block): lane l ends with sum of red[l]
    #pragma unroll
    for (int s = 0; s < 6; ++s) {
        const int m = 1 << s;
        const int b = (lane >> s) & 1;
        #pragma unroll
        for (int u = 0; u < (64 >> (s + 1)); ++u) {
            const float lo = red[2 * u];
            const float hi = red[2 * u + 1];
            const float send = b ? lo : hi;
            const float recv = __shfl_xor(send, m, 64);
            const float kept = b ? hi : lo;
            red[u] = kept + recv;
        }
    }

    // contiguous 256B store per wave: tpart[h][row0 + (lane>>4)][lane&15]
    tpart[((size_t)h * M_ROWS + row0) * 16 + lane] = red[0];
}

// ---------------------------------------------------------------------------
// Kernel 2: out = t @ B^T. Block = 16 rows x 1024 cols, 256 threads.
// Thread owns 4 consecutive output cols; B values for those cols live in
// registers (contiguous 256B per thread, L1/L2-hot). tpart (2 slabs) summed
// into 1 KB LDS, broadcast. Stores: 1KB coalesced bursts.
__global__ __launch_bounds__(256, 4) void lora_tb(const float* __restrict__ tpart,
                                                  const float* __restrict__ B,
                                                  float* __restrict__ out) {
    __shared__ float4 t_s4[64];           // 16 rows x 16 r

    const int tid = threadIdx.x;
    const int rb  = blockIdx.x >> 2;      // 16-row tile
    const int cb  = blockIdx.x & 3;       // 1024-col chunk

    // B into registers: 4 cols x 16 r = 256B contiguous per thread
    const int o0 = cb * 1024 + tid * 4;   // first of 4 output cols
    float4 breg[4][4];
    const float4* B4 = (const float4*)B;
    #pragma unroll
    for (int j = 0; j < 4; ++j)
        #pragma unroll
        for (int q = 0; q < 4; ++q)
            breg[j][q] = B4[(size_t)(o0 + j) * 4 + q];

    if (tid < 64) {
        const float4* p4 = (const float4*)tpart;
        float4 a = p4[(size_t)rb * 64 + tid];
        const float4 b = p4[(size_t)TP_F4_STRIDE + rb * 64 + tid];
        a.x += b.x; a.y += b.y; a.z += b.z; a.w += b.w;
        t_s4[tid] = a;                    // t[rb*16 + ...] row*4+q layout
    }
    __syncthreads();

    float4* out4 = (float4*)out;
    const int c4 = cb * 256 + tid;        // float4 column index

    #pragma unroll
    for (int row = 0; row < 16; ++row) {
        float4 tq[4];
        #pragma unroll
        for (int q = 0; q < 4; ++q)
            tq[q] = t_s4[row * 4 + q];    // LDS broadcast (same addr all lanes)
        float o0v = 0.f, o1v = 0.f, o2v = 0.f, o3v = 0.f;
        #pragma unroll
        for (int r = 0; r < 16; ++r) {
            const float4 tv4 = tq[r >> 2];
            const float tv = ((r & 3) == 0) ? tv4.x :
                             ((r & 3) == 1) ? tv4.y :
                             ((r & 3) == 2) ? tv4.z : tv4.w;
            o0v = fmaf(tv, ((const float*)&breg[0][0])[r], o0v);
            o1v = fmaf(tv, ((const float*)&breg[1][0])[r], o1v);
            o2v = fmaf(tv, ((const float*)&breg[2][0])[r], o2v);
            o3v = fmaf(tv, ((const float*)&breg[3][0])[r], o3v);
        }
        const float4 o = {o0v, o1v, o2v, o3v};
        out4[(size_t)(rb * 16 + row) * NF + c4] = o;
    }
}

extern "C" void kernel_launch(void* const* d_in, const int* in_sizes, int n_in,
                              void* d_out, int out_size, void* d_ws, size_t ws_size,
                              hipStream_t stream) {
    const float* x = (const float*)d_in[0];            // [4,2048,4096]
    const float* B = (const float*)d_in[1];            // [4096,16]
    const float* A = (const float*)d_in[2];            // [16,4096]
    float* out = (float*)d_out;                        // [4,2048,4096]

    float* tpart = (float*)d_ws;                       // [2][8192][16], 1 MB

    lora_xat<<<NTILES * KSPLIT, 256, 0, stream>>>(x, A, tpart);
    lora_tb<<<NTILES * (N_DIM / 1024), 256, 0, stream>>>(tpart, B, out);
}

// Round 11
// 66.401 us; speedup vs baseline: 1.6227x; 1.2534x over previous
//
#include <hip/hip_runtime.h>

#define K_DIM   4096
#define N_DIM   4096
#define M_ROWS  8192
#define KF      (K_DIM / 4)      // 1024 float4 per x/A row
#define NF      (N_DIM / 4)      // 1024 float4 per out row
#define KSPLIT  8
#define KCH     (KF / KSPLIT)    // 128 float4 per K-chunk
#define NTILES  (M_ROWS / 16)    // 512 row tiles
#define TP_F4_STRIDE (M_ROWS * 16 / 4)   // 32768 float4 per k-partial slab

#define FMA4(accv, xv, av)                         \
    do {                                           \
        accv = fmaf((xv).x, (av).x, accv);         \
        accv = fmaf((xv).y, (av).y, accv);         \
        accv = fmaf((xv).z, (av).z, accv);         \
        accv = fmaf((xv).w, (av).w, accv);         \
    } while (0)

// ---------------------------------------------------------------------------
// Kernel 1: t partials. Grid = NTILES*KSPLIT = 4096 blocks, 256 thr
// (4 waves x 4 rows = 16 rows, one 128-f4 K-chunk per block).
// Stall-window merge: it=0 x loads issued BEFORE A staging, so the ds_write's
// FIFO vmcnt wait drains A and x in ONE window; it=1 x loads issued right
// after the barrier so their latency hides under it=0's 256 FMA instrs.
// All static indices (rule #20); peak regs ~122 -> 4 waves/SIMD, no spill.
__global__ __launch_bounds__(256, 4) void lora_xat(const float* __restrict__ x,
                                                   const float* __restrict__ A,
                                                   float* __restrict__ tpart) {
    __shared__ float4 Alds[16 * KCH];     // 32 KB

    const int tid  = threadIdx.x;
    const int wv   = tid >> 6;            // wave -> 4-row group
    const int lane = tid & 63;
    const int rb   = blockIdx.x >> 3;     // 16-row tile
    const int h    = blockIdx.x & 7;      // K eighth
    const int row0 = rb * 16 + wv * 4;
    const int kbase = h * KCH;            // float4 units

    const float4* x4 = (const float4*)x;
    const float4* A4 = (const float4*)A;

    // (1) it=0 x loads — first in the vmcnt FIFO
    const float4 xa0 = x4[(size_t)(row0 + 0) * KF + kbase + lane];
    const float4 xa1 = x4[(size_t)(row0 + 1) * KF + kbase + lane];
    const float4 xa2 = x4[(size_t)(row0 + 2) * KF + kbase + lane];
    const float4 xa3 = x4[(size_t)(row0 + 3) * KF + kbase + lane];

    // (2) A staging: regs -> LDS (ds_write waits A *and* xa: one window)
    {
        float4 areg[8];
        #pragma unroll
        for (int i = 0; i < 8; ++i) {
            const int idx = i * 256 + tid;
            areg[i] = A4[(idx >> 7) * KF + kbase + (idx & (KCH - 1))];
        }
        #pragma unroll
        for (int i = 0; i < 8; ++i)
            Alds[i * 256 + tid] = areg[i];
    }                                     // areg dead here

    float red[64];
    #pragma unroll
    for (int v = 0; v < 64; ++v) red[v] = 0.f;

    __syncthreads();                      // Alds ready

    // (3) it=1 x loads — latency hides under it=0 FMA block
    const float4 xb0 = x4[(size_t)(row0 + 0) * KF + kbase + 64 + lane];
    const float4 xb1 = x4[(size_t)(row0 + 1) * KF + kbase + 64 + lane];
    const float4 xb2 = x4[(size_t)(row0 + 2) * KF + kbase + 64 + lane];
    const float4 xb3 = x4[(size_t)(row0 + 3) * KF + kbase + 64 + lane];

    // (4) FMA it=0 (xa*, Alds col = lane)
    #pragma unroll
    for (int r = 0; r < 16; ++r) {
        const float4 av = Alds[r * KCH + lane];   // conflict-free b128
        FMA4(red[0 * 16 + r], xa0, av);
        FMA4(red[1 * 16 + r], xa1, av);
        FMA4(red[2 * 16 + r], xa2, av);
        FMA4(red[3 * 16 + r], xa3, av);
    }
    // (5) FMA it=1 (xb*, Alds col = 64 + lane)
    #pragma unroll
    for (int r = 0; r < 16; ++r) {
        const float4 av = Alds[r * KCH + 64 + lane];
        FMA4(red[0 * 16 + r], xb0, av);
        FMA4(red[1 * 16 + r], xb1, av);
        FMA4(red[2 * 16 + r], xb2, av);
        FMA4(red[3 * 16 + r], xb3, av);
    }

    // in-wave butterfly: lane l ends with sum over lanes of red[l]
    #pragma unroll
    for (int s = 0; s < 6; ++s) {
        const int m = 1 << s;
        const int b = (lane >> s) & 1;
        #pragma unroll
        for (int u = 0; u < (64 >> (s + 1)); ++u) {
            const float lo = red[2 * u];
            const float hi = red[2 * u + 1];
            const float send = b ? lo : hi;
            const float recv = __shfl_xor(send, m, 64);
            const float kept = b ? hi : lo;
            red[u] = kept + recv;
        }
    }

    // contiguous 256B store per wave: tpart[h][row0 + (lane>>4)][lane&15]
    tpart[((size_t)h * M_ROWS + row0) * 16 + lane] = red[0];
}

// ---------------------------------------------------------------------------
// Kernel 2: out = t @ B^T. Block = 16 rows x 1024 cols, 256 threads.
// (Byte-identical to the proven round-7 kernel.)
__global__ __launch_bounds__(256, 4) void lora_tb(const float* __restrict__ tpart,
                                                  const float* __restrict__ B,
                                                  float* __restrict__ out) {
    __shared__ float4 tp_s[4][64];
    __shared__ float4 t_s4[64];           // 16 rows x 16 r

    const int tid = threadIdx.x;
    const int rb  = blockIdx.x >> 2;      // 16-row tile
    const int cb  = blockIdx.x & 3;       // 1024-col chunk

    // B into registers: 4 cols x 16 r = 256B contiguous per thread
    const int o0 = cb * 1024 + tid * 4;   // first of 4 output cols
    float4 breg[4][4];
    const float4* B4 = (const float4*)B;
    #pragma unroll
    for (int j = 0; j < 4; ++j)
        #pragma unroll
        for (int q = 0; q < 4; ++q)
            breg[j][q] = B4[(size_t)(o0 + j) * 4 + q];

    // parallel tpart sum: 8 slabs -> 4 partials -> 1
    {
        const int f  = tid & 63;
        const int hp = tid >> 6;          // 0..3
        const float4* p4 = (const float4*)tpart;
        float4 a = p4[(size_t)(2 * hp) * TP_F4_STRIDE + rb * 64 + f];
        const float4 b = p4[(size_t)(2 * hp + 1) * TP_F4_STRIDE + rb * 64 + f];
        a.x += b.x; a.y += b.y; a.z += b.z; a.w += b.w;
        tp_s[hp][f] = a;
    }
    __syncthreads();
    if (tid < 64) {
        float4 s = tp_s[0][tid];
        #pragma unroll
        for (int hp = 1; hp < 4; ++hp) {
            const float4 q = tp_s[hp][tid];
            s.x += q.x; s.y += q.y; s.z += q.z; s.w += q.w;
        }
        t_s4[tid] = s;                    // t[rb*16 + ...] row*4+q layout
    }
    __syncthreads();

    float4* out4 = (float4*)out;
    const int c4 = cb * 256 + tid;        // float4 column index

    #pragma unroll
    for (int row = 0; row < 16; ++row) {
        float4 tq[4];
        #pragma unroll
        for (int q = 0; q < 4; ++q)
            tq[q] = t_s4[row * 4 + q];    // LDS broadcast (same addr all lanes)
        float o0v = 0.f, o1v = 0.f, o2v = 0.f, o3v = 0.f;
        #pragma unroll
        for (int r = 0; r < 16; ++r) {
            const float4 tv4 = tq[r >> 2];
            const float tv = ((r & 3) == 0) ? tv4.x :
                             ((r & 3) == 1) ? tv4.y :
                             ((r & 3) == 2) ? tv4.z : tv4.w;
            o0v = fmaf(tv, ((const float*)&breg[0][0])[r], o0v);
            o1v = fmaf(tv, ((const float*)&breg[1][0])[r], o1v);
            o2v = fmaf(tv, ((const float*)&breg[2][0])[r], o2v);
            o3v = fmaf(tv, ((const float*)&breg[3][0])[r], o3v);
        }
        const float4 o = {o0v, o1v, o2v, o3v};
        out4[(size_t)(rb * 16 + row) * NF + c4] = o;
    }
}

extern "C" void kernel_launch(void* const* d_in, const int* in_sizes, int n_in,
                              void* d_out, int out_size, void* d_ws, size_t ws_size,
                              hipStream_t stream) {
    const float* x = (const float*)d_in[0];            // [4,2048,4096]
    const float* B = (const float*)d_in[1];            // [4096,16]
    const float* A = (const float*)d_in[2];            // [16,4096]
    float* out = (float*)d_out;                        // [4,2048,4096]

    float* tpart = (float*)d_ws;                       // [8][8192][16], 4 MB

    lora_xat<<<NTILES * KSPLIT, 256, 0, stream>>>(x, A, tpart);
    lora_tb<<<NTILES * (N_DIM / 1024), 256, 0, stream>>>(tpart, B, out);
}

// Round 12
// 65.707 us; speedup vs baseline: 1.6398x; 1.0106x over previous
//
#include <hip/hip_runtime.h>

#define K_DIM   4096
#define N_DIM   4096
#define M_ROWS  8192
#define KF      (K_DIM / 4)      // 1024 float4 per x/A row
#define NF      (N_DIM / 4)      // 1024 float4 per out row
#define KSPLIT  8
#define NTILES  (M_ROWS / 16)    // 512 row tiles (for k2 grid)
#define TP_F4_STRIDE (M_ROWS * 16 / 4)   // 32768 float4 per k-partial slab

typedef __attribute__((ext_vector_type(8))) short short8v;   // 8 bf16
typedef __attribute__((ext_vector_type(4))) float f32x4;

// round-to-nearest-even fp32 -> bf16 bits
static __device__ __forceinline__ short f2bf(float f) {
    const unsigned u = __builtin_bit_cast(unsigned, f);
    return (short)((u + 0x7FFFu + ((u >> 16) & 1u)) >> 16);
}

// ---------------------------------------------------------------------------
// Kernel 1 (MFMA): t partials. Grid = (M/64)*KSPLIT = 1024 blocks, 256 thr.
// Wave w owns rows [rb*64 + w*16, +16) and K-eighth h. Per K=32 step, one
// v_mfma_f32_16x16x32_bf16 computes the full 16x16 (rows x r) product:
//   A-op lane l = x[row0 + (l&15)][kc + (l>>4)*8 + e]   (e = 0..7)
//   B-op lane l = A[(l&15)][kc + (l>>4)*8 + e]
//   C    lane l reg v = t[row0 + (l>>4)*4 + v][l&15]
// Wave reads 16 rows x 128B per step: full-line utilization. acc = 4 VGPRs.
__global__ __launch_bounds__(256) void lora_xat(const float* __restrict__ x,
                                                const float* __restrict__ A,
                                                float* __restrict__ tpart) {
    const int tid  = threadIdx.x;
    const int wv   = tid >> 6;
    const int lane = tid & 63;
    const int rb   = blockIdx.x >> 3;     // 64-row tile
    const int h    = blockIdx.x & 7;      // K eighth
    const int row0 = rb * 64 + wv * 16;

    const int mrow = row0 + (lane & 15);  // x row this lane feeds (A-op)
    const int acol = lane & 15;           // A-matrix row = t column (B-op)
    const int og   = (lane >> 4) * 2;     // lane-group's float4 pair in octet

    const float4* x4 = (const float4*)x;
    const float4* A4 = (const float4*)A;
    const size_t xbase = (size_t)mrow * KF;
    const size_t abase = (size_t)acol * KF;

    f32x4 acc = {0.f, 0.f, 0.f, 0.f};

    #pragma unroll 4
    for (int it = 0; it < 16; ++it) {
        const int kf = h * 128 + it * 8 + og;   // float4 index within row
        const float4 xa = x4[xbase + kf];
        const float4 xb = x4[xbase + kf + 1];
        const float4 aa = A4[abase + kf];
        const float4 ab = A4[abase + kf + 1];

        short8v af, bf;
        af[0] = f2bf(xa.x); af[1] = f2bf(xa.y);
        af[2] = f2bf(xa.z); af[3] = f2bf(xa.w);
        af[4] = f2bf(xb.x); af[5] = f2bf(xb.y);
        af[6] = f2bf(xb.z); af[7] = f2bf(xb.w);
        bf[0] = f2bf(aa.x); bf[1] = f2bf(aa.y);
        bf[2] = f2bf(aa.z); bf[3] = f2bf(aa.w);
        bf[4] = f2bf(ab.x); bf[5] = f2bf(ab.y);
        bf[6] = f2bf(ab.z); bf[7] = f2bf(ab.w);

        acc = __builtin_amdgcn_mfma_f32_16x16x32_bf16(af, bf, acc, 0, 0, 0);
    }

    // C layout: lane l reg v -> row (l>>4)*4+v, col l&15
    #pragma unroll
    for (int v = 0; v < 4; ++v) {
        const int orow = row0 + (lane >> 4) * 4 + v;
        tpart[((size_t)h * M_ROWS + orow) * 16 + (lane & 15)] = acc[v];
    }
}

// ---------------------------------------------------------------------------
// Kernel 2: out = t @ B^T. Block = 16 rows x 1024 cols, 256 threads.
// (Byte-identical to the proven round-7 kernel.)
__global__ __launch_bounds__(256, 4) void lora_tb(const float* __restrict__ tpart,
                                                  const float* __restrict__ B,
                                                  float* __restrict__ out) {
    __shared__ float4 tp_s[4][64];
    __shared__ float4 t_s4[64];           // 16 rows x 16 r

    const int tid = threadIdx.x;
    const int rb  = blockIdx.x >> 2;      // 16-row tile
    const int cb  = blockIdx.x & 3;       // 1024-col chunk

    // B into registers: 4 cols x 16 r = 256B contiguous per thread
    const int o0 = cb * 1024 + tid * 4;   // first of 4 output cols
    float4 breg[4][4];
    const float4* B4 = (const float4*)B;
    #pragma unroll
    for (int j = 0; j < 4; ++j)
        #pragma unroll
        for (int q = 0; q < 4; ++q)
            breg[j][q] = B4[(size_t)(o0 + j) * 4 + q];

    // parallel tpart sum: 8 slabs -> 4 partials -> 1
    {
        const int f  = tid & 63;
        const int hp = tid >> 6;          // 0..3
        const float4* p4 = (const float4*)tpart;
        float4 a = p4[(size_t)(2 * hp) * TP_F4_STRIDE + rb * 64 + f];
        const float4 b = p4[(size_t)(2 * hp + 1) * TP_F4_STRIDE + rb * 64 + f];
        a.x += b.x; a.y += b.y; a.z += b.z; a.w += b.w;
        tp_s[hp][f] = a;
    }
    __syncthreads();
    if (tid < 64) {
        float4 s = tp_s[0][tid];
        #pragma unroll
        for (int hp = 1; hp < 4; ++hp) {
            const float4 q = tp_s[hp][tid];
            s.x += q.x; s.y += q.y; s.z += q.z; s.w += q.w;
        }
        t_s4[tid] = s;                    // t[rb*16 + ...] row*4+q layout
    }
    __syncthreads();

    float4* out4 = (float4*)out;
    const int c4 = cb * 256 + tid;        // float4 column index

    #pragma unroll
    for (int row = 0; row < 16; ++row) {
        float4 tq[4];
        #pragma unroll
        for (int q = 0; q < 4; ++q)
            tq[q] = t_s4[row * 4 + q];    // LDS broadcast (same addr all lanes)
        float o0v = 0.f, o1v = 0.f, o2v = 0.f, o3v = 0.f;
        #pragma unroll
        for (int r = 0; r < 16; ++r) {
            const float4 tv4 = tq[r >> 2];
            const float tv = ((r & 3) == 0) ? tv4.x :
                             ((r & 3) == 1) ? tv4.y :
                             ((r & 3) == 2) ? tv4.z : tv4.w;
            o0v = fmaf(tv, ((const float*)&breg[0][0])[r], o0v);
            o1v = fmaf(tv, ((const float*)&breg[1][0])[r], o1v);
            o2v = fmaf(tv, ((const float*)&breg[2][0])[r], o2v);
            o3v = fmaf(tv, ((const float*)&breg[3][0])[r], o3v);
        }
        const float4 o = {o0v, o1v, o2v, o3v};
        out4[(size_t)(rb * 16 + row) * NF + c4] = o;
    }
}

extern "C" void kernel_launch(void* const* d_in, const int* in_sizes, int n_in,
                              void* d_out, int out_size, void* d_ws, size_t ws_size,
                              hipStream_t stream) {
    const float* x = (const float*)d_in[0];            // [4,2048,4096]
    const float* B = (const float*)d_in[1];            // [4096,16]
    const float* A = (const float*)d_in[2];            // [16,4096]
    float* out = (float*)d_out;                        // [4,2048,4096]

    float* tpart = (float*)d_ws;                       // [8][8192][16], 4 MB

    lora_xat<<<(M_ROWS / 64) * KSPLIT, 256, 0, stream>>>(x, A, tpart);
    lora_tb<<<NTILES * (N_DIM / 1024), 256, 0, stream>>>(tpart, B, out);
}

// Round 13
// 62.814 us; speedup vs baseline: 1.7154x; 1.0461x over previous
//
#include <hip/hip_runtime.h>

#define K_DIM   4096
#define N_DIM   4096
#define M_ROWS  8192
#define KF      (K_DIM / 4)      // 1024 float4 per x/A row
#define NF      (N_DIM / 4)      // 1024 float4 per out/Bt row
#define KSPLIT  8
#define NTILES  (M_ROWS / 16)    // 512 row tiles (k2 grid)
#define TP_F4_STRIDE (M_ROWS * 16 / 4)   // 32768 float4 per k-partial slab
#define XAT_BLOCKS ((M_ROWS / 64) * KSPLIT)   // 1024
#define TRB_BLOCKS 64                         // folded B-transpose blocks

typedef __attribute__((ext_vector_type(8))) short short8v;   // 8 bf16
typedef __attribute__((ext_vector_type(4))) float f32x4;

// round-to-nearest-even fp32 -> bf16 bits
static __device__ __forceinline__ short f2bf(float f) {
    const unsigned u = __builtin_bit_cast(unsigned, f);
    return (short)((u + 0x7FFFu + ((u >> 16) & 1u)) >> 16);
}

// ---------------------------------------------------------------------------
// Kernel 1 (MFMA + folded B-transpose).
// Blocks [0, 1024): t partials, identical to round 12 (proven absmax 0.125).
// Blocks [1024, 1088): transpose B [4096][16] -> Bt [16][4096] (runs
// concurrently with the MFMA blocks; k2 depends on both).
__global__ __launch_bounds__(256) void lora_xat(const float* __restrict__ x,
                                                const float* __restrict__ A,
                                                const float* __restrict__ B,
                                                float* __restrict__ Bt,
                                                float* __restrict__ tpart) {
    const int tid = threadIdx.x;

    if (blockIdx.x >= XAT_BLOCKS) {
        // ---- B transpose: 64 blocks x 256 thr x 1 float4 of Bt ----
        const int i4 = (blockIdx.x - XAT_BLOCKS) * 256 + tid;  // 0..16383
        const int r  = i4 >> 10;             // Bt row 0..15
        const int c0 = (i4 & 1023) * 4;      // first of 4 cols
        float4 v;
        v.x = B[(size_t)(c0 + 0) * 16 + r];
        v.y = B[(size_t)(c0 + 1) * 16 + r];
        v.z = B[(size_t)(c0 + 2) * 16 + r];
        v.w = B[(size_t)(c0 + 3) * 16 + r];
        ((float4*)Bt)[i4] = v;
        return;
    }

    const int wv   = tid >> 6;
    const int lane = tid & 63;
    const int rb   = blockIdx.x >> 3;     // 64-row tile
    const int h    = blockIdx.x & 7;      // K eighth
    const int row0 = rb * 64 + wv * 16;

    const int mrow = row0 + (lane & 15);  // x row this lane feeds (A-op)
    const int acol = lane & 15;           // A-matrix row = t column (B-op)
    const int og   = (lane >> 4) * 2;     // lane-group's float4 pair in octet

    const float4* x4 = (const float4*)x;
    const float4* A4 = (const float4*)A;
    const size_t xbase = (size_t)mrow * KF;
    const size_t abase = (size_t)acol * KF;

    f32x4 acc = {0.f, 0.f, 0.f, 0.f};

    #pragma unroll 4
    for (int it = 0; it < 16; ++it) {
        const int kf = h * 128 + it * 8 + og;   // float4 index within row
        const float4 xa = x4[xbase + kf];
        const float4 xb = x4[xbase + kf + 1];
        const float4 aa = A4[abase + kf];
        const float4 ab = A4[abase + kf + 1];

        short8v af, bf;
        af[0] = f2bf(xa.x); af[1] = f2bf(xa.y);
        af[2] = f2bf(xa.z); af[3] = f2bf(xa.w);
        af[4] = f2bf(xb.x); af[5] = f2bf(xb.y);
        af[6] = f2bf(xb.z); af[7] = f2bf(xb.w);
        bf[0] = f2bf(aa.x); bf[1] = f2bf(aa.y);
        bf[2] = f2bf(aa.z); bf[3] = f2bf(aa.w);
        bf[4] = f2bf(ab.x); bf[5] = f2bf(ab.y);
        bf[6] = f2bf(ab.z); bf[7] = f2bf(ab.w);

        acc = __builtin_amdgcn_mfma_f32_16x16x32_bf16(af, bf, acc, 0, 0, 0);
    }

    // C layout: lane l reg v -> row (l>>4)*4+v, col l&15
    #pragma unroll
    for (int v = 0; v < 4; ++v) {
        const int orow = row0 + (lane >> 4) * 4 + v;
        tpart[((size_t)h * M_ROWS + orow) * 16 + (lane & 15)] = acc[v];
    }
}

// ---------------------------------------------------------------------------
// Kernel 2: out = t @ B^T using pre-transposed Bt. Block = 16 rows x 1024
// cols, 256 threads. bv[16] loaded as 16 fully-coalesced 1KB wave bursts
// (replaces the 64-segment B-gather). tpart (8 slabs) summed via LDS.
__global__ __launch_bounds__(256) void lora_tb(const float* __restrict__ tpart,
                                               const float* __restrict__ Bt,
                                               float* __restrict__ out) {
    __shared__ float4 tp_s[4][64];
    __shared__ float4 t_s4[64];           // 16 rows x 16 r

    const int tid = threadIdx.x;
    const int rb  = blockIdx.x >> 2;      // 16-row tile
    const int cb  = blockIdx.x & 3;       // 1024-col chunk
    const int c4  = cb * 256 + tid;       // float4 column index

    const float4* Bt4 = (const float4*)Bt;
    float4 bv[16];
    #pragma unroll
    for (int r = 0; r < 16; ++r)
        bv[r] = Bt4[r * NF + c4];         // 1KB contiguous per instr, L2-hot

    // parallel tpart sum: 8 slabs -> 4 partials -> 1
    {
        const int f  = tid & 63;
        const int hp = tid >> 6;          // 0..3
        const float4* p4 = (const float4*)tpart;
        float4 a = p4[(size_t)(2 * hp) * TP_F4_STRIDE + rb * 64 + f];
        const float4 b = p4[(size_t)(2 * hp + 1) * TP_F4_STRIDE + rb * 64 + f];
        a.x += b.x; a.y += b.y; a.z += b.z; a.w += b.w;
        tp_s[hp][f] = a;
    }
    __syncthreads();
    if (tid < 64) {
        float4 s = tp_s[0][tid];
        #pragma unroll
        for (int hp = 1; hp < 4; ++hp) {
            const float4 q = tp_s[hp][tid];
            s.x += q.x; s.y += q.y; s.z += q.z; s.w += q.w;
        }
        t_s4[tid] = s;                    // t[rb*16 + ...] row*4+q layout
    }
    __syncthreads();

    float4* out4 = (float4*)out;

    #pragma unroll
    for (int row = 0; row < 16; ++row) {
        float4 tq[4];
        #pragma unroll
        for (int q = 0; q < 4; ++q)
            tq[q] = t_s4[row * 4 + q];    // LDS broadcast (same addr all lanes)
        float4 o = {0.f, 0.f, 0.f, 0.f};
        #pragma unroll
        for (int r = 0; r < 16; ++r) {
            const float4 tv4 = tq[r >> 2];
            const float tv = ((r & 3) == 0) ? tv4.x :
                             ((r & 3) == 1) ? tv4.y :
                             ((r & 3) == 2) ? tv4.z : tv4.w;
            o.x = fmaf(tv, bv[r].x, o.x);
            o.y = fmaf(tv, bv[r].y, o.y);
            o.z = fmaf(tv, bv[r].z, o.z);
            o.w = fmaf(tv, bv[r].w, o.w);
        }
        out4[(size_t)(rb * 16 + row) * NF + c4] = o;
    }
}

extern "C" void kernel_launch(void* const* d_in, const int* in_sizes, int n_in,
                              void* d_out, int out_size, void* d_ws, size_t ws_size,
                              hipStream_t stream) {
    const float* x = (const float*)d_in[0];            // [4,2048,4096]
    const float* B = (const float*)d_in[1];            // [4096,16]
    const float* A = (const float*)d_in[2];            // [16,4096]
    float* out = (float*)d_out;                        // [4,2048,4096]

    float* Bt    = (float*)d_ws;                       // [16][4096], 256 KB
    float* tpart = Bt + 16 * N_DIM;                    // [8][8192][16], 4 MB

    lora_xat<<<XAT_BLOCKS + TRB_BLOCKS, 256, 0, stream>>>(x, A, B, Bt, tpart);
    lora_tb<<<NTILES * (N_DIM / 1024), 256, 0, stream>>>(tpart, Bt, out);
}